// Round 5
// baseline (6634.457 us; speedup 1.0000x reference)
//
#include <hip/hip_runtime.h>
#include <hip/hip_fp16.h>
#include <stdint.h>

typedef _Float16 h8 __attribute__((ext_vector_type(8)));
typedef float f4 __attribute__((ext_vector_type(4)));

#define MFMA16(a, b, c) __builtin_amdgcn_mfma_f32_16x16x32_f16((a), (b), (c), 0, 0, 0)

#define RSLOT 16

constexpr size_t HBUF_OFF = 0;
constexpr size_t HBUF_BYTES = 10ull * RSLOT * 64 * 64 * 8 * 2;   // 10,485,760
constexpr size_t X_OFF = HBUF_OFF + HBUF_BYTES;
constexpr size_t X_BYTES = 256ull * 4096 * 2;                    // 2,097,152
constexpr size_t STRM_OFF = X_OFF + X_BYTES;
constexpr size_t STRM_BYTES = 234ull * 15360;                    // 3,594,240
constexpr size_t PROG_OFF = STRM_OFF + STRM_BYTES;               // 16,177,152 (64B aligned)
constexpr int PROG_WORDS = 352;   // layers 0..9 at L*32+cl, head at 320+hd
constexpr size_t WS_NEED = PROG_OFF + PROG_WORDS * 4;

// L2-bypassing (agent-coherent) 16B load; hand-counted vmcnt stream.
__device__ __forceinline__ h8 gld16_sc1(const void* base, int voff) {
  h8 v;
  asm volatile("global_load_dwordx4 %0, %1, %2 sc1"
               : "=v"(v) : "v"(voff), "s"(base));
  return v;
}
// cached 16B load in the same hand-counted stream (immutable data)
__device__ __forceinline__ h8 gld16_c(const void* base, int voff) {
  h8 v;
  asm volatile("global_load_dwordx4 %0, %1, %2"
               : "=v"(v) : "v"(voff), "s"(base));
  return v;
}
// counted wait + scheduling fence
#define WAITV(N) do { asm volatile("s_waitcnt vmcnt(" #N ")" ::: "memory"); \
                      __builtin_amdgcn_sched_barrier(0); } while (0)

// device-coherent 2B store (write-through to coherence point)
__device__ __forceinline__ void st_h_dc(__half* p, float x) {
  __hip_atomic_store((unsigned short*)p, __half_as_ushort(__float2half(x)),
                     __ATOMIC_RELAXED, __HIP_MEMORY_SCOPE_AGENT);
}

__device__ __forceinline__ int ld_prog(const int* p) {
  return __hip_atomic_load(p, __ATOMIC_RELAXED, __HIP_MEMORY_SCOPE_AGENT);
}
__device__ __forceinline__ void st_prog(int* p, int v) {
  __hip_atomic_store(p, v, __ATOMIC_RELAXED, __HIP_MEMORY_SCOPE_AGENT);
  __builtin_amdgcn_sched_barrier(0);   // don't let it sink past the next poll
}

__device__ __forceinline__ int colrow_main(int c, int S, int hbase) {
  int g, hl;
  if (c < 64) { g = c >> 4; hl = c & 15; }
  else { int j = c - 64; g = j & 3; hl = 16 + (j >> 2); }
  if (hl >= S) hl = S - 1;
  return g * 512 + hbase + hl;
}

__device__ __forceinline__ float sigm(float x) {
  return __fdividef(1.f, 1.f + __expf(-x));
}
__device__ __forceinline__ float tanh_f(float x) {
  return 1.f - __fdividef(2.f, __expf(2.f * x) + 1.f);
}

// ---------------- prep kernels ----------------

__global__ __launch_bounds__(256) void zero_kernel(char* ws) {
  int i = blockIdx.x * 256 + threadIdx.x;
  if (i < 163840) {                        // zero slot 0 of each layer's h ring
    int layer = i >> 14;
    int w = i & 16383;
    ((int*)(ws + HBUF_OFF))[(size_t)layer * RSLOT * 16384 + w] = 0;
  } else {
    int j = i - 163840;
    if (j < PROG_WORDS) ((int*)(ws + PROG_OFF))[j] = -1;
  }
}

__global__ __launch_bounds__(256) void xprep_kernel(const float* __restrict__ X, char* ws) {
  int u = blockIdx.x * 256 + threadIdx.x;
  if (u >= 131072) return;
  int t = u >> 9, rem = u & 511, kg = rem >> 6, b = rem & 63;
  const float* src = X + ((size_t)b * 256 + t) * 64 + kg * 8;
  h8 v;
#pragma unroll
  for (int j = 0; j < 8; ++j) v[j] = (_Float16)src[j];
  *(h8*)(ws + X_OFF + (size_t)u * 16) = v;
}

__global__ __launch_bounds__(256) void wsprep_kernel(const float* __restrict__ Whh, char* ws) {
  int u = blockIdx.x * 256 + threadIdx.x;
  if (u >= 234 * 15 * 64) return;
  int cu = u / 960, rem = u % 960;
  int f = rem >> 6, l = rem & 63;
  int ktm = f / 5, nt = f % 5, kt = 29 + ktm;
  int L = 1 + cu / 26, cl = cu % 26;
  int S = cl < 18 ? 20 : 19;
  int hbase = cl < 18 ? 20 * cl : 360 + 19 * (cl - 18);
  int c = 16 * nt + (l & 15);
  int row = colrow_main(c, S, hbase);
  int k = kt * 32 + (l >> 4) * 8;
  const float* src = Whh + ((size_t)L * 2048 + row) * 512 + (k - 512);
  h8 v;
#pragma unroll
  for (int j = 0; j < 8; ++j) v[j] = (_Float16)src[j];
  *(h8*)(ws + STRM_OFF + (size_t)cu * 15360 + (size_t)f * 1024 + (size_t)l * 16) = v;
}

// ---------------- main persistent kernel ----------------

// K-body for layers 1..9: 5 cols (c = 16j+pp)
#define KB(kt, Av) do {                                                        \
  if ((kt) < 29) {                                                             \
    _Pragma("unroll")                                                          \
    for (int j_ = 0; j_ < 5; ++j_) {                                           \
      int c_ = 16 * j_ + pp;                                                   \
      uint32_t off_ = (uint32_t)(c_ * 1856 + (kt) * 64 + lg * 16)              \
                    ^ (uint32_t)((c_ & 7) << 4);                               \
      h8 bv_ = *(const h8*)(lds + off_);                                       \
      acc[j_] = MFMA16((Av), bv_, acc[j_]);                                    \
    }                                                                          \
  } else {                                                                     \
    _Pragma("unroll")                                                          \
    for (int j_ = 0; j_ < 5; ++j_) {                                           \
      h8 bv_ = *(const h8*)(lds + 148480 + (((kt) - 29) * 5 + j_) * 1024       \
                            + lane * 16);                                      \
      acc[j_] = MFMA16((Av), bv_, acc[j_]);                                    \
    }                                                                          \
  }                                                                            \
} while (0)

// K-body for layer 0: 8 cols, stride 1152
#define KB0(kt, Av) do {                                                       \
  _Pragma("unroll")                                                            \
  for (int j_ = 0; j_ < 8; ++j_) {                                             \
    int c_ = 16 * j_ + pp;                                                     \
    uint32_t off_ = (uint32_t)(c_ * 1152 + (kt) * 64 + lg * 16)                \
                  ^ (uint32_t)((c_ & 7) << 4);                                 \
    h8 bv_ = *(const h8*)(lds + off_);                                         \
    acc[j_] = MFMA16((Av), bv_, acc[j_]);                                      \
  }                                                                            \
} while (0)

// head dot-product chunk: 16 kg of h9 against 3 Wout rows
#define KH(kb, H) do {                                                         \
  _Pragma("unroll")                                                            \
  for (int i_ = 0; i_ < 16; ++i_) {                                            \
    int kg_ = (kb) + i_;                                                       \
    h8 hv_ = H[i_];                                                            \
    float hf_[8];                                                              \
    _Pragma("unroll")                                                          \
    for (int j_ = 0; j_ < 8; ++j_) hf_[j_] = (float)hv_[j_];                   \
    if (a0ok) {                                                                \
      f4 w0_ = *(const f4*)(wrow0 + kg_ * 8);                                  \
      f4 w1_ = *(const f4*)(wrow0 + kg_ * 8 + 4);                              \
      a0 += hf_[0]*w0_[0] + hf_[1]*w0_[1] + hf_[2]*w0_[2] + hf_[3]*w0_[3]      \
          + hf_[4]*w1_[0] + hf_[5]*w1_[1] + hf_[6]*w1_[2] + hf_[7]*w1_[3];     \
    }                                                                          \
    if (a1ok) {                                                                \
      f4 w0_ = *(const f4*)(wrow1 + kg_ * 8);                                  \
      f4 w1_ = *(const f4*)(wrow1 + kg_ * 8 + 4);                              \
      a1 += hf_[0]*w0_[0] + hf_[1]*w0_[1] + hf_[2]*w0_[2] + hf_[3]*w0_[3]      \
          + hf_[4]*w1_[0] + hf_[5]*w1_[1] + hf_[6]*w1_[2] + hf_[7]*w1_[3];     \
    }                                                                          \
    if (a2ok) {                                                                \
      f4 w0_ = *(const f4*)(wrow2 + kg_ * 8);                                  \
      f4 w1_ = *(const f4*)(wrow2 + kg_ * 8 + 4);                              \
      a2 += hf_[0]*w0_[0] + hf_[1]*w0_[1] + hf_[2]*w0_[2] + hf_[3]*w0_[3]      \
          + hf_[4]*w1_[0] + hf_[5]*w1_[1] + hf_[6]*w1_[2] + hf_[7]*w1_[3];     \
    }                                                                          \
  }                                                                            \
} while (0)

__global__ __launch_bounds__(256, 1) void lstm_fused(
    const float* __restrict__ X, const float* __restrict__ Wih0,
    const float* __restrict__ Wih, const float* __restrict__ Whh,
    const float* __restrict__ bih, const float* __restrict__ bhh,
    const float* __restrict__ Wout, const float* __restrict__ bout,
    float* __restrict__ out, char* __restrict__ ws)
{
  extern __shared__ char lds[];
  const int blk = blockIdx.x;
  const int role = (blk & 7) * 32 + (blk >> 3);   // XCD-contiguous role mapping

  __half* hbuf = (__half*)(ws + HBUF_OFF);
  const __half* xt = (const __half*)(ws + X_OFF);
  int* prog = (int*)(ws + PROG_OFF);

  const int tid = threadIdx.x;
  const int lane = tid & 63;
  const int wv = tid >> 6;
  const int pp = lane & 15;
  const int lg = lane >> 4;
  // per-wave A fragment byte offset within a k-tile: wave owns b-rows [16wv,16wv+16)
  const int abb = lg * 1024 + (16 * wv + pp) * 16;

  if (role >= 250) {
    // ================= head on 6 spare CUs =================
    const int hd = role - 250;
    const int d0 = hd * 11;
    const int nd = (hd < 5) ? 11 : 9;
    const int b = lane;
    const float* wrow0 = Wout + (size_t)(d0 + wv + 0) * 512;
    const float* wrow1 = Wout + (size_t)(d0 + wv + 4) * 512;
    const float* wrow2 = Wout + (size_t)(d0 + wv + 8) * 512;
    const bool a0ok = (wv + 0) < nd;
    const bool a1ok = (wv + 4) < nd;
    const bool a2ok = (wv + 8) < nd;
    int* myp = prog + 320 + hd;
    const int* pw = prog + 9 * 32 + lane;   // lanes 0..25: layer-9 CUs; 32..63: head grp (ignored)
    const bool pv = lane < 26;
    for (int th = 0; th < 256; ++th) {
      if (wv == 0) {
        int it = 0;
        for (;;) {
          int v = ld_prog(pw);
          if (__ballot(!pv || v >= th) == ~0ull) break;
          __builtin_amdgcn_s_sleep(1);
          if (++it > 100000) break;
        }
      }
      __builtin_amdgcn_s_barrier();
      const __half* h9 = hbuf + ((size_t)9 * RSLOT + ((th + 1) & 15)) * 32768;
      h8 H0[16], H1[16], H2[16], H3[16];
#pragma unroll
      for (int i = 0; i < 16; ++i) H0[i] = gld16_sc1(h9, i * 1024 + b * 16);
#pragma unroll
      for (int i = 0; i < 16; ++i) H1[i] = gld16_sc1(h9, (16 + i) * 1024 + b * 16);
      float a0 = a0ok ? bout[d0 + wv + 0] : 0.f;
      float a1 = a1ok ? bout[d0 + wv + 4] : 0.f;
      float a2 = a2ok ? bout[d0 + wv + 8] : 0.f;
      WAITV(16);
      KH(0, H0);
#pragma unroll
      for (int i = 0; i < 16; ++i) H2[i] = gld16_sc1(h9, (32 + i) * 1024 + b * 16);
      WAITV(16);
      KH(16, H1);
#pragma unroll
      for (int i = 0; i < 16; ++i) H3[i] = gld16_sc1(h9, (48 + i) * 1024 + b * 16);
      WAITV(16);
      KH(32, H2);
      WAITV(0);
      KH(48, H3);
      if (a0ok) out[(size_t)b * 16384 + (size_t)th * 64 + d0 + wv + 0] = a0;
      if (a1ok) out[(size_t)b * 16384 + (size_t)th * 64 + d0 + wv + 4] = a1;
      if (a2ok) out[(size_t)b * 16384 + (size_t)th * 64 + d0 + wv + 8] = a2;
      __syncthreads();   // h9 fully consumed by this CU
      if (tid == 0) st_prog(myp, th);
    }
    return;
  }

  if (role < 16) {
    // ================= layer 0 (pure cell) =================
    const int cu = role;
    const int hbase = cu * 32;
    for (int ch = tid; ch < 9216; ch += 256) {
      int c = ch / 72, kc = (ch % 72) * 8;
      int g = (c >> 4) & 3;
      int hl = ((c >> 6) << 4) + (c & 15);
      int row = g * 512 + hbase + hl;
      const float* src = (kc < 64) ? (Wih0 + (size_t)row * 64 + kc)
                                   : (Whh + (size_t)row * 512 + (kc - 64));
      h8 v;
#pragma unroll
      for (int j = 0; j < 8; ++j) v[j] = (_Float16)src[j];
      uint32_t off = ((uint32_t)(c * 1152 + kc * 2)) ^ (uint32_t)((c & 7) << 4);
      *(h8*)(lds + off) = v;
    }
    float bias0[8];
#pragma unroll
    for (int j = 0; j < 8; ++j) {
      int row = (j & 3) * 512 + hbase + ((j >> 2) << 4) + pp;
      bias0[j] = bih[row] + bhh[row];
    }
    __syncthreads();

    float cv0[2][4] = {{0.f,0.f,0.f,0.f},{0.f,0.f,0.f,0.f}};
    int* myp = prog + cu;
    // poll: lanes 0..31 -> own layer (valid<16, tgt t-1); 32..63 -> layer1 (valid<26, tgt t-15)
    const int* pw = prog + lane;
    const bool pv = (lane < 32) ? (lane < 16) : ((lane - 32) < 26);

    for (int t = 0; t < 256; ++t) {
      if (wv == 0) {
        int tgt = (lane < 32) ? t - 1 : t - 15;
        int it = 0;
        for (;;) {
          int v = ld_prog(pw);
          if (__ballot(!pv || v >= tgt) == ~0ull) break;
          __builtin_amdgcn_s_sleep(1);
          if (++it > 100000) break;
        }
      }
      __builtin_amdgcn_s_barrier();
      const __half* As = hbuf + (size_t)(t & 15) * 32768;
      // hand-counted load stream: 2 x-loads, then 16 recurrent loads
      h8 X0 = gld16_c(xt, (int)((size_t)t * 8192) + lg * 1024 + (16 * wv + pp) * 16);
      h8 X1 = gld16_c(xt, (int)((size_t)t * 8192) + 4096 + lg * 1024 + (16 * wv + pp) * 16);
      h8 A0[8], A1[8];
#pragma unroll
      for (int i = 0; i < 8; ++i) A0[i] = gld16_sc1(As, i * 4096 + abb);
#pragma unroll
      for (int i = 0; i < 8; ++i) A1[i] = gld16_sc1(As, (8 + i) * 4096 + abb);
      f4 acc[8];
#pragma unroll
      for (int j = 0; j < 8; ++j) acc[j] = (f4){0.f, 0.f, 0.f, 0.f};
      WAITV(16);
      KB0(0, X0);
      KB0(1, X1);
      WAITV(8);
#pragma unroll
      for (int i = 0; i < 8; ++i) KB0(2 + i, A0[i]);
      WAITV(0);
#pragma unroll
      for (int i = 0; i < 8; ++i) KB0(10 + i, A1[i]);
      // epilogue: thread owns h cols {hbase+pp, hbase+16+pp}, rows 16wv+4lg+r
      __half* Hd = hbuf + (size_t)((t + 1) & 15) * 32768;
      const int brow = 16 * wv + 4 * lg;
#pragma unroll
      for (int jh = 0; jh < 2; ++jh) {
        const int hg = hbase + jh * 16 + pp;
#pragma unroll
        for (int r = 0; r < 4; ++r) {
          float gi = sigm(acc[4*jh+0][r] + bias0[4*jh+0]);
          float gf = sigm(acc[4*jh+1][r] + bias0[4*jh+1]);
          float gg = tanh_f(acc[4*jh+2][r] + bias0[4*jh+2]);
          float go = sigm(acc[4*jh+3][r] + bias0[4*jh+3]);
          float cc = gf * cv0[jh][r] + gi * gg;
          cv0[jh][r] = cc;
          st_h_dc(Hd + (size_t)(hg >> 3) * 512 + (brow + r) * 8 + (hg & 7),
                  go * tanh_f(cc));
        }
      }
      __syncthreads();   // drains stores before publish
      if (tid == 0) st_prog(myp, t);
    }
    return;
  }

  // ================= layers 1..9 =================
  const int cuIdx = role - 16;
  const int L = 1 + cuIdx / 26;
  const int cl = cuIdx % 26;
  const int S = cl < 18 ? 20 : 19;
  const int hbase = cl < 18 ? 20 * cl : 360 + 19 * (cl - 18);
  const float* WihL = Wih + (size_t)(L - 1) * 1048576;
  const float* WhhL = Whh + (size_t)L * 1048576;
  const float* bihL = bih + L * 2048;
  const float* bhhL = bhh + L * 2048;

  // weights kt 0..28 into LDS [80 cols][928 k], stride 1856B, XOR swizzle
  for (int ch = tid; ch < 9280; ch += 256) {
    int c = ch / 116, kc = (ch % 116) * 8;
    int row = colrow_main(c, S, hbase);
    const float* src = (kc < 512) ? (WihL + (size_t)row * 512 + kc)
                                  : (WhhL + (size_t)row * 512 + (kc - 512));
    h8 v;
#pragma unroll
    for (int j = 0; j < 8; ++j) v[j] = (_Float16)src[j];
    uint32_t off = ((uint32_t)(c * 1856 + kc * 2)) ^ (uint32_t)((c & 7) << 4);
    *(h8*)(lds + off) = v;
  }
  // streamed kt 29..31 fragments into LDS tail [148480, 163840)
  {
    const char* strmg = ws + STRM_OFF + (size_t)cuIdx * 15360;
    for (int ch = tid; ch < 960; ch += 256)
      *(h8*)(lds + 148480 + ch * 16) = *(const h8*)(strmg + ch * 16);
  }
  float biasv[4], bsp[4];
#pragma unroll
  for (int j = 0; j < 4; ++j) {
    int row = colrow_main(16 * j + pp, S, hbase);
    biasv[j] = bihL[row] + bhhL[row];
    int rs = colrow_main(64 + 4 * (pp >> 2) + j, S, hbase);
    bsp[j] = bihL[rs] + bhhL[rs];
  }
  __syncthreads();

  const int cntB = (L == 1) ? 16 : 26;
  const int pm = lane & 3;
  const int hj = 16 + (pp >> 2);
  int* myp = prog + L * 32 + cl;
  // load1: lanes 0..31 below layer (tgt t), 32..63 own layer (tgt t-1)
  const int* pw1 = prog + (L - 1) * 32 + lane;
  const bool pv1 = (lane < 32) ? (lane < cntB) : ((lane - 32) < 26);
  // load2: lanes 0..31 above group (ring guard, tgt t-15)
  const int baseA = (L == 9) ? 320 : (L + 1) * 32;
  const int cntA = (L == 9) ? 6 : 26;
  const int* pw2 = prog + baseA + (lane & 31);
  const bool pv2 = (lane < 32) && (lane < cntA);

  float cv[4] = {0.f,0.f,0.f,0.f};
  float csp[4] = {0.f,0.f,0.f,0.f};

  for (int t = 0; t < 256; ++t) {
    if (wv == 0) {
      int tgt1 = (lane < 32) ? t : t - 1;
      int tgt2 = t - 15;
      int it = 0;
      for (;;) {
        int v1 = ld_prog(pw1);
        int v2 = ld_prog(pw2);
        bool ok = (!pv1 || v1 >= tgt1) && (!pv2 || v2 >= tgt2);
        if (__ballot(ok) == ~0ull) break;
        __builtin_amdgcn_s_sleep(1);
        if (++it > 100000) break;
      }
    }
    __builtin_amdgcn_s_barrier();

    const __half* Abot = hbuf + ((size_t)(L - 1) * RSLOT + ((t + 1) & 15)) * 32768;
    const __half* Asel = hbuf + ((size_t)L * RSLOT + (t & 15)) * 32768;
    h8 A0[8], A1[8], A2[8], A3[8];
#pragma unroll
    for (int i = 0; i < 8; ++i) A0[i] = gld16_sc1(Abot, i * 4096 + abb);
#pragma unroll
    for (int i = 0; i < 8; ++i) A1[i] = gld16_sc1(Abot, (8 + i) * 4096 + abb);
#pragma unroll
    for (int i = 0; i < 8; ++i) A2[i] = gld16_sc1(Asel, i * 4096 + abb);
#pragma unroll
    for (int i = 0; i < 8; ++i) A3[i] = gld16_sc1(Asel, (8 + i) * 4096 + abb);
    f4 acc[5];
#pragma unroll
    for (int j = 0; j < 5; ++j) acc[j] = (f4){0.f, 0.f, 0.f, 0.f};
    WAITV(24);
#pragma unroll
    for (int i = 0; i < 8; ++i) KB(i, A0[i]);
    WAITV(16);
#pragma unroll
    for (int i = 0; i < 8; ++i) KB(8 + i, A1[i]);
    WAITV(8);
#pragma unroll
    for (int i = 0; i < 8; ++i) KB(16 + i, A2[i]);
    WAITV(0);
#pragma unroll
    for (int i = 0; i < 8; ++i) KB(24 + i, A3[i]);

    // epilogue: thread owns h col hbase+pp (4 gates in-thread) + spare via 4-lane gather
    __half* Hd = hbuf + ((size_t)L * RSLOT + ((t + 1) & 15)) * 32768;
    const int brow = 16 * wv + 4 * lg;
    const int hgm = hbase + pp;
#pragma unroll
    for (int r = 0; r < 4; ++r) {
      float gi = sigm(acc[0][r] + biasv[0]);
      float gf = sigm(acc[1][r] + biasv[1]);
      float gg = tanh_f(acc[2][r] + biasv[2]);
      float go = sigm(acc[3][r] + biasv[3]);
      float cc = gf * cv[r] + gi * gg;
      cv[r] = cc;
      st_h_dc(Hd + (size_t)(hgm >> 3) * 512 + (brow + r) * 8 + (hgm & 7),
              go * tanh_f(cc));
      // spare col (c = 64+pp): gate = pm, h = 16+(pp>>2); gather 4 gates in 4-lane group
      float va = acc[4][r];
      float vb = __shfl_xor(va, 1);
      float vc = __shfl_xor(va, 2);
      float vd = __shfl_xor(vb, 2);
      float q0 = (pm & 2) ? ((pm & 1) ? vd : vc) : ((pm & 1) ? vb : va);
      float q1 = (pm & 2) ? ((pm & 1) ? vc : vd) : ((pm & 1) ? va : vb);
      float q2 = (pm & 2) ? ((pm & 1) ? vb : va) : ((pm & 1) ? vd : vc);
      float q3 = (pm & 2) ? ((pm & 1) ? va : vb) : ((pm & 1) ? vc : vd);
      float si = sigm(q0 + bsp[0]);
      float sf = sigm(q1 + bsp[1]);
      float sg = tanh_f(q2 + bsp[2]);
      float so = sigm(q3 + bsp[3]);
      float c3 = sf * csp[r] + si * sg;
      csp[r] = c3;
      if (pm == 0 && hj < S) {
        int hg = hbase + hj;
        st_h_dc(Hd + (size_t)(hg >> 3) * 512 + (brow + r) * 8 + (hg & 7),
                so * tanh_f(c3));
      }
    }

    __syncthreads();   // drains stores before publish
    if (tid == 0) st_prog(myp, t);
  }
}

// ---------------- host ----------------

extern "C" void kernel_launch(void* const* d_in, const int* in_sizes, int n_in,
                              void* d_out, int out_size, void* d_ws, size_t ws_size,
                              hipStream_t stream) {
  const float* X    = (const float*)d_in[0];
  const float* Wih0 = (const float*)d_in[1];
  const float* Wih  = (const float*)d_in[2];
  const float* Whh  = (const float*)d_in[3];
  const float* bihp = (const float*)d_in[4];
  const float* bhhp = (const float*)d_in[5];
  const float* Wout = (const float*)d_in[6];
  const float* bout = (const float*)d_in[7];
  float* out = (float*)d_out;
  char* ws = (char*)d_ws;
  (void)in_sizes; (void)n_in; (void)out_size;
  if (ws_size < WS_NEED) return;

  hipFuncSetAttribute((const void*)lstm_fused,
                      hipFuncAttributeMaxDynamicSharedMemorySize, 163840);

  zero_kernel<<<642, 256, 0, stream>>>(ws);
  xprep_kernel<<<512, 256, 0, stream>>>(X, ws);
  wsprep_kernel<<<878, 256, 0, stream>>>(Whh, ws);
  lstm_fused<<<256, 256, 163840, stream>>>(X, Wih0, Wih, Whh, bihp, bhhp,
                                           Wout, bout, out, ws);
}

// Round 7
// 3677.708 us; speedup vs baseline: 1.8040x; 1.8040x over previous
//
#include <hip/hip_runtime.h>
#include <hip/hip_fp16.h>
#include <stdint.h>

typedef _Float16 h8 __attribute__((ext_vector_type(8)));
typedef float f4 __attribute__((ext_vector_type(4)));

#define MFMA16(a,b,c) __builtin_amdgcn_mfma_f32_16x16x32_f16((a),(b),(c),0,0,0)

// ---------------- ws memory map ----------------
constexpr size_t XT_OFF = 0;                       // [256 t][8 kg][64 b][8h] fp16
constexpr size_t XT_BYTES = 256ull * 4096 * 2;     // 2 MB
constexpr size_t HL_OFF = XT_OFF + XT_BYTES;       // plain h rings [10 L][8 slot][64KB]
constexpr size_t HL_BYTES = 10ull * 8 * 65536;
constexpr size_t HX_OFF = HL_OFF + HL_BYTES;       // sc1 h rings (odd L) [5][8][64KB]
constexpr size_t HX_BYTES = 5ull * 8 * 65536;
constexpr size_t WSTRM_OFF = HX_OFF + HX_BYTES;    // streamed W frags [144 cu][12 kt][8 nt][1KB]
constexpr size_t WSTRM_BYTES = 144ull * 98304;
constexpr size_t PX_OFF = WSTRM_OFF + WSTRM_BYTES; // progX[168] sc1 flags (L*16+cl; 160..167 head)
constexpr size_t CNT_OFF = PX_OFF + 1024;          // xcd claim counters[8]
constexpr size_t DIAG_OFF = CNT_OFF + 64;          // bail diagnostic word
constexpr size_t WS_NEED = DIAG_OFF + 64;

// ---------------- asm load helpers (hand-counted vmcnt stream) ----------------
__device__ __forceinline__ h8 gld16_p(const void* base, int voff) {
  h8 v; asm volatile("global_load_dwordx4 %0, %1, %2" : "=v"(v) : "v"(voff), "s"(base)); return v;
}
__device__ __forceinline__ h8 gld16_sc1(const void* base, int voff) {
  h8 v; asm volatile("global_load_dwordx4 %0, %1, %2 sc1" : "=v"(v) : "v"(voff), "s"(base)); return v;
}
#define WAITI(n) do { asm volatile("s_waitcnt vmcnt(" #n ")" ::: "memory"); \
                      __builtin_amdgcn_sched_barrier(0); } while (0)

// plain 2B store: write-through vL1 -> home-XCD L2 (intra-XCD consumers)
__device__ __forceinline__ void st_h_p(__half* p, float x) {
  *(volatile unsigned short*)p = __half_as_ushort(__float2half(x));
}
// device-coherent 2B store (to L3, for cross-XCD readers)
__device__ __forceinline__ void st_h_dc(__half* p, float x) {
  __hip_atomic_store((unsigned short*)p, __half_as_ushort(__float2half(x)),
                     __ATOMIC_RELAXED, __HIP_MEMORY_SCOPE_AGENT);
}
__device__ __forceinline__ int ld_prog(const int* p) {
  return __hip_atomic_load(p, __ATOMIC_RELAXED, __HIP_MEMORY_SCOPE_AGENT);
}
__device__ __forceinline__ void st_prog(int* p, int v) {
  __hip_atomic_store(p, v, __ATOMIC_RELAXED, __HIP_MEMORY_SCOPE_AGENT);
  __builtin_amdgcn_sched_barrier(0);
}
// vL1 invalidate: makes subsequent plain loads see home-L2 freshness
#define INV_L1() asm volatile("buffer_inv sc0\n\ts_waitcnt vmcnt(0)" ::: "memory")

__device__ __forceinline__ float sigm(float x) { return __fdividef(1.f, 1.f + __expf(-x)); }
__device__ __forceinline__ float tanh_f(float x) { return 1.f - __fdividef(2.f, __expf(2.f*x) + 1.f); }

// ---------------- prep kernels ----------------
__global__ __launch_bounds__(256) void zero_kernel(char* ws) {
  int i = blockIdx.x * 256 + threadIdx.x;
  if (i < 163840) {                       // hL slot 0 of each layer = h(-1) = 0
    int layer = i >> 14, w = i & 16383;
    ((int*)(ws + HL_OFF))[(size_t)layer * 8 * 16384 + w] = 0;
  } else {
    int j = i - 163840;
    if (j < 168) ((int*)(ws + PX_OFF))[j] = -1;
    else if (j < 176) ((int*)(ws + CNT_OFF))[j - 168] = 0;
    else if (j == 176) ((int*)(ws + DIAG_OFF))[0] = 0;
  }
}

__global__ __launch_bounds__(256) void xprep_kernel(const float* __restrict__ X, char* ws) {
  int u = blockIdx.x * 256 + threadIdx.x;
  if (u >= 131072) return;
  int t = u >> 9, rem = u & 511, kg = rem >> 6, b = rem & 63;
  const float* src = X + ((size_t)b * 256 + t) * 64 + kg * 8;
  h8 v;
#pragma unroll
  for (int j = 0; j < 8; ++j) v[j] = (_Float16)src[j];
  *(h8*)(ws + XT_OFF + (size_t)u * 16) = v;
}

// pack streamed W_ih kt 4..15 into per-lane fragment layout
__global__ __launch_bounds__(256) void wsprep_kernel(const float* __restrict__ Wih, char* ws) {
  int u = blockIdx.x * 256 + threadIdx.x;
  if (u >= 144 * 6144) return;
  int cu = u / 6144, rem = u % 6144;
  int kt4 = rem / 512, rem2 = rem % 512;
  int nt = rem2 >> 6, l = rem2 & 63;
  int ppc = l >> 2, lgc = l & 3;
  int L = 1 + cu / 16, cl = cu % 16, hbase = cl * 32;
  int kt = 4 + kt4, k = kt * 32 + lgc * 8;
  int row = (nt & 3) * 512 + hbase + ((nt >> 2) << 4) + ppc;
  const float* src = Wih + (size_t)(L - 1) * 1048576 + (size_t)row * 512 + k;
  h8 v;
#pragma unroll
  for (int j = 0; j < 8; ++j) v[j] = (_Float16)src[j];
  uint32_t off = (uint32_t)(ppc * 64 + lgc * 16) ^ (uint32_t)((ppc & 7) << 4);
  *(h8*)(ws + WSTRM_OFF + (size_t)cu * 98304 + (size_t)kt4 * 8192 + (size_t)nt * 1024 + off) = v;
}

// ---------------- main persistent kernel ----------------
#define KTRES(r, Wn, Areg) do { WAITI(Wn);                                      \
  _Pragma("unroll") for (int nt_ = 0; nt_ < 8; ++nt_) {                         \
    h8 bv_ = *(const h8*)(lds + ((((r) * 8 + nt_) << 10) + swzo));              \
    acc[nt_] = MFMA16((Areg), bv_, acc[nt_]); } } while (0)

#define KTSTR(s, Wn, Areg) do { WAITI(Wn);                                      \
  _Pragma("unroll") for (int nt_ = 0; nt_ < 8; ++nt_)                           \
    acc[nt_] = MFMA16((Areg), Bst[s][nt_], acc[nt_]); } while (0)

#define ISSB(s) do { _Pragma("unroll") for (int nt_ = 0; nt_ < 8; ++nt_)        \
    Bst[s][nt_] = gld16_p(strm, (s) * 8192 + (nt_ << 10) + (int)swzo); } while (0)

#define ISSAS(i0) do { _Pragma("unroll") for (int i_ = 0; i_ < 4; ++i_)         \
    AS[(i0) + i_] = gld16_p(selb, ((i0) + i_) * 4096 + abb); } while (0)

__global__ __launch_bounds__(256, 1) void lstm_fused(
    const float* __restrict__ X, const float* __restrict__ Wih0,
    const float* __restrict__ Wih, const float* __restrict__ Whh,
    const float* __restrict__ bih, const float* __restrict__ bhh,
    const float* __restrict__ Wout, const float* __restrict__ bout,
    float* __restrict__ out, char* __restrict__ ws)
{
  extern __shared__ char lds[];
  const int tid = threadIdx.x;
  const int lane = tid & 63;
  const int wv = tid >> 6;
  const int pp = lane & 15;
  const int lg = lane >> 4;
  const int abb = lg * 1024 + (16 * wv + pp) * 16;
  const uint32_t swzo = (uint32_t)(pp * 64 + lg * 16) ^ (uint32_t)((pp & 7) << 4);

  int* progX = (int*)(ws + PX_OFF);
  int* diag  = (int*)(ws + DIAG_OFF);

  // ---- discover physical XCD, claim a role slot within it ----
  int xcd;
  asm volatile("s_getreg_b32 %0, hwreg(HW_REG_XCC_ID)" : "=s"(xcd));
  xcd &= 7;
  if (tid == 0) {
    int s = atomicAdd((int*)(ws + CNT_OFF) + xcd, 1);
    *(int*)lds = s;
  }
  __syncthreads();
  const int slot = *(int*)lds;
  __syncthreads();

  // ================= head (XCD 5, slots 0..7) =================
  if (xcd == 5) {
    if (slot >= 8) return;
    const int hd = slot, d0 = hd * 8;
    const float* wrow0 = Wout + (size_t)(d0 + wv) * 512;
    const float* wrow1 = Wout + (size_t)(d0 + 4 + wv) * 512;
    const int b = lane;
    const bool pv = lane < 16;
    const int* pw = progX + 144 + (lane & 15);
    for (int th = 0; th < 256; ++th) {
      if (wv == 0) {
        int it = 0; bool bailed = false;
        for (;;) {
          int v = ld_prog(pw);
          if (__ballot(!pv || v >= th) == ~0ull) break;
          __builtin_amdgcn_s_sleep(1);
          if (++it > 60000) { bailed = true; break; }
        }
        if (bailed && lane == 0) atomicMax(diag, 10000 + th);
      }
      __builtin_amdgcn_s_barrier();
      const char* h9 = ws + HX_OFF + (size_t)(4 * 8 + ((th + 1) & 7)) * 65536;
      h8 H0[16], H1[16], H2[16], H3[16];
#pragma unroll
      for (int i = 0; i < 16; ++i) H0[i] = gld16_sc1(h9, i * 1024 + b * 16);
#pragma unroll
      for (int i = 0; i < 16; ++i) H1[i] = gld16_sc1(h9, (16 + i) * 1024 + b * 16);
      float a0 = bout[d0 + wv], a1 = bout[d0 + 4 + wv];
#define KH(kb, H) do { _Pragma("unroll") for (int i_ = 0; i_ < 16; ++i_) {      \
        h8 hv_ = H[i_]; float hf_[8];                                           \
        _Pragma("unroll") for (int j_ = 0; j_ < 8; ++j_) hf_[j_] = (float)hv_[j_]; \
        int kg_ = (kb) + i_;                                                    \
        f4 w0_ = *(const f4*)(wrow0 + kg_ * 8); f4 w1_ = *(const f4*)(wrow0 + kg_ * 8 + 4); \
        a0 += hf_[0]*w0_[0]+hf_[1]*w0_[1]+hf_[2]*w0_[2]+hf_[3]*w0_[3]           \
            + hf_[4]*w1_[0]+hf_[5]*w1_[1]+hf_[6]*w1_[2]+hf_[7]*w1_[3];          \
        f4 u0_ = *(const f4*)(wrow1 + kg_ * 8); f4 u1_ = *(const f4*)(wrow1 + kg_ * 8 + 4); \
        a1 += hf_[0]*u0_[0]+hf_[1]*u0_[1]+hf_[2]*u0_[2]+hf_[3]*u0_[3]           \
            + hf_[4]*u1_[0]+hf_[5]*u1_[1]+hf_[6]*u1_[2]+hf_[7]*u1_[3]; } } while (0)
      WAITI(16); KH(0, H0);
#pragma unroll
      for (int i = 0; i < 16; ++i) H2[i] = gld16_sc1(h9, (32 + i) * 1024 + b * 16);
      WAITI(16); KH(16, H1);
#pragma unroll
      for (int i = 0; i < 16; ++i) H3[i] = gld16_sc1(h9, (48 + i) * 1024 + b * 16);
      WAITI(16); KH(32, H2);
      WAITI(0);  KH(48, H3);
      out[(size_t)b * 16384 + (size_t)th * 64 + d0 + wv] = a0;
      out[(size_t)b * 16384 + (size_t)th * 64 + d0 + 4 + wv] = a1;
      __syncthreads();
      if (tid == 0) st_prog(progX + 160 + hd, th);
    }
    // diagnostic: surface any recorded stall code (zero in healthy runs)
    if (hd == 0 && tid == 0) {
      int dv = ld_prog(diag);
      if (dv != 0) out[0] = 1.0e6f + (float)dv;
    }
    return;
  }
  if (xcd > 5 || slot >= 32) return;

  // ================= layer CUs: XCD k hosts layers 2k, 2k+1 =================
  const int L = 2 * xcd + (slot >= 16);
  const int cl = slot & 15;
  const int hbase = cl * 32;
  const bool oddL = (L & 1) != 0;

  // ---- stage resident weights into LDS (fragment layout + swizzle) ----
  if (L == 0) {
    for (int ch = tid; ch < 9216; ch += 256) {   // 18 kt: 0,1=x(Wih0) 2..17=h(Whh0)
      int r = ch >> 9, rem = ch & 511;
      int nt = rem >> 6, l = rem & 63, ppc = l >> 2, lgc = l & 3;
      int k = r * 32 + lgc * 8;
      int row = (nt & 3) * 512 + hbase + ((nt >> 2) << 4) + ppc;
      const float* src = (k < 64) ? (Wih0 + (size_t)row * 64 + k)
                                  : (Whh + (size_t)row * 512 + (k - 64));
      h8 v;
#pragma unroll
      for (int j = 0; j < 8; ++j) v[j] = (_Float16)src[j];
      uint32_t off = (uint32_t)(ppc * 64 + lgc * 16) ^ (uint32_t)((ppc & 7) << 4);
      *(h8*)(lds + ((r * 8 + nt) << 10) + off) = v;
    }
  } else {
    const float* WihL = Wih + (size_t)(L - 1) * 1048576;
    const float* WhhL = Whh + (size_t)L * 1048576;
    for (int ch = tid; ch < 10240; ch += 256) {  // r0..3 -> kt0..3, r4..19 -> kt16..31
      int r = ch >> 9, rem = ch & 511;
      int nt = rem >> 6, l = rem & 63, ppc = l >> 2, lgc = l & 3;
      int rkt = r < 4 ? r : r + 12;
      int k = rkt * 32 + lgc * 8;
      int row = (nt & 3) * 512 + hbase + ((nt >> 2) << 4) + ppc;
      const float* src = (k < 512) ? (WihL + (size_t)row * 512 + k)
                                   : (WhhL + (size_t)row * 512 + (k - 512));
      h8 v;
#pragma unroll
      for (int j = 0; j < 8; ++j) v[j] = (_Float16)src[j];
      uint32_t off = (uint32_t)(ppc * 64 + lgc * 16) ^ (uint32_t)((ppc & 7) << 4);
      *(h8*)(lds + ((r * 8 + nt) << 10) + off) = v;
    }
  }
  float biasv[8];
#pragma unroll
  for (int nt = 0; nt < 8; ++nt) {
    int row = (nt & 3) * 512 + hbase + ((nt >> 2) << 4) + pp;
    biasv[nt] = bih[L * 2048 + row] + bhh[L * 2048 + row];
  }
  __syncthreads();

  // ---- poll descriptors: lanes 0-15 own(t-1), 16-31 below(t), 32-47 above(t-7) ----
  const int jl = lane & 15;
  const int* pw = progX; bool pv = false; int dlt = 0;
  if (lane < 16)      { pv = true; pw = progX + L * 16 + jl; dlt = -1; }
  else if (lane < 32) { if (L > 0) { pv = true; pw = progX + (L - 1) * 16 + jl; dlt = 0; } }
  else if (lane < 48) {
    dlt = -7;
    if (L == 9) { if (jl < 8) { pv = true; pw = progX + 160 + jl; } }
    else        { pv = true; pw = progX + (L + 1) * 16 + jl; }
  }

  const char* hl = ws + HL_OFF;
  const char* hx = ws + HX_OFF;
  const char* strm = ws + WSTRM_OFF + (size_t)((L - 1) * 16 + cl) * 98304;  // L>=1
  const char* xt = ws + XT_OFF;

  float cv[2][4] = {{0,0,0,0},{0,0,0,0}};

  for (int t = 0; t < 256; ++t) {
    if (wv == 0) {
      int it = 0; bool bailed = false;
      for (;;) {
        int v = ld_prog(pw);
        if (__ballot(!pv || v >= t + dlt) == ~0ull) break;
        __builtin_amdgcn_s_sleep(1);
        if (++it > 60000) { bailed = true; break; }
      }
      if (bailed && lane == 0) atomicMax(diag, L * 1000 + t);
      INV_L1();   // vL1 invalidate so plain loads below see home-L2 state
    }
    __builtin_amdgcn_s_barrier();

    f4 acc[8];
#pragma unroll
    for (int j = 0; j < 8; ++j) acc[j] = (f4){0.f, 0.f, 0.f, 0.f};

    if (L == 0) {
      const char* selb = hl + (size_t)(t & 7) * 65536;
      h8 X0 = gld16_p(xt, t * 8192 + abb);
      h8 X1 = gld16_p(xt, t * 8192 + 4096 + abb);
      h8 AS[16];
#pragma unroll
      for (int i = 0; i < 16; ++i) AS[i] = gld16_p(selb, i * 4096 + abb);
      KTRES(0, 17, X0);
      KTRES(1, 16, X1);
      KTRES(2, 15, AS[0]);  KTRES(3, 14, AS[1]);  KTRES(4, 13, AS[2]);  KTRES(5, 12, AS[3]);
      KTRES(6, 11, AS[4]);  KTRES(7, 10, AS[5]);  KTRES(8, 9, AS[6]);   KTRES(9, 8, AS[7]);
      KTRES(10, 7, AS[8]);  KTRES(11, 6, AS[9]);  KTRES(12, 5, AS[10]); KTRES(13, 4, AS[11]);
      KTRES(14, 3, AS[12]); KTRES(15, 2, AS[13]); KTRES(16, 1, AS[14]); KTRES(17, 0, AS[15]);
    } else {
      const char* botb = oddL ? (hl + (size_t)((L - 1) * 8 + ((t + 1) & 7)) * 65536)
                              : (hx + (size_t)(((L - 1) >> 1) * 8 + ((t + 1) & 7)) * 65536);
      const char* selb = hl + (size_t)(L * 8 + (t & 7)) * 65536;
      h8 AB[16], AS[16], Bst[12][8];
      if (oddL) {
#pragma unroll
        for (int i = 0; i < 16; ++i) AB[i] = gld16_p(botb, i * 4096 + abb);
      } else {
#pragma unroll
        for (int i = 0; i < 16; ++i) AB[i] = gld16_sc1(botb, i * 4096 + abb);
      }
      ISSB(0); ISSB(1);
      KTRES(0, 31, AB[0]);  ISSB(2);
      KTRES(1, 38, AB[1]);  ISSB(3);
      KTRES(2, 45, AB[2]);  ISSB(4);
      KTRES(3, 52, AB[3]);  ISSB(5);
      KTSTR(0, 40, AB[4]);  ISSB(6);
      KTSTR(1, 40, AB[5]);  ISSB(7);
      KTSTR(2, 40, AB[6]);  ISSB(8);
      KTSTR(3, 40, AB[7]);  ISSB(9);
      KTSTR(4, 40, AB[8]);  ISSB(10);
      KTSTR(5, 40, AB[9]);  ISSB(11);
      KTSTR(6, 40, AB[10]); ISSAS(0);
      KTSTR(7, 36, AB[11]); ISSAS(4);
      KTSTR(8, 32, AB[12]); ISSAS(8);
      KTSTR(9, 28, AB[13]); ISSAS(12);
      KTSTR(10, 24, AB[14]);
      KTSTR(11, 16, AB[15]);
      KTRES(4, 15, AS[0]);  KTRES(5, 14, AS[1]);  KTRES(6, 13, AS[2]);  KTRES(7, 12, AS[3]);
      KTRES(8, 11, AS[4]);  KTRES(9, 10, AS[5]);  KTRES(10, 9, AS[6]);  KTRES(11, 8, AS[7]);
      KTRES(12, 7, AS[8]);  KTRES(13, 6, AS[9]);  KTRES(14, 5, AS[10]); KTRES(15, 4, AS[11]);
      KTRES(16, 3, AS[12]); KTRES(17, 2, AS[13]); KTRES(18, 1, AS[14]); KTRES(19, 0, AS[15]);
    }

    // ---- epilogue: thread owns all 4 gates for h = hbase + jh*16 + pp ----
    __half* HdL = (__half*)(hl + (size_t)(L * 8 + ((t + 1) & 7)) * 65536);
    __half* HdX = oddL ? (__half*)(hx + (size_t)((L >> 1) * 8 + ((t + 1) & 7)) * 65536) : nullptr;
    const int brow = 16 * wv + 4 * lg;
#pragma unroll
    for (int jh = 0; jh < 2; ++jh) {
      const int hg = hbase + jh * 16 + pp;
      const size_t hoff = (size_t)(hg >> 3) * 512 + (hg & 7);
#pragma unroll
      for (int r = 0; r < 4; ++r) {
        float gi = sigm(acc[4*jh+0][r] + biasv[4*jh+0]);
        float gf = sigm(acc[4*jh+1][r] + biasv[4*jh+1]);
        float gg = tanh_f(acc[4*jh+2][r] + biasv[4*jh+2]);
        float go = sigm(acc[4*jh+3][r] + biasv[4*jh+3]);
        float cc = gf * cv[jh][r] + gi * gg;
        cv[jh][r] = cc;
        float hh = go * tanh_f(cc);
        st_h_p(HdL + hoff + (size_t)(brow + r) * 8, hh);
        if (oddL) st_h_dc(HdX + hoff + (size_t)(brow + r) * 8, hh);
      }
    }

    __syncthreads();   // drains plain stores (L2-acked) + sc1 stores (L3-acked)
    if (tid == 0) st_prog(progX + L * 16 + cl, t);
  }
}

// ---------------- host ----------------
extern "C" void kernel_launch(void* const* d_in, const int* in_sizes, int n_in,
                              void* d_out, int out_size, void* d_ws, size_t ws_size,
                              hipStream_t stream) {
  const float* X    = (const float*)d_in[0];
  const float* Wih0 = (const float*)d_in[1];
  const float* Wih  = (const float*)d_in[2];
  const float* Whh  = (const float*)d_in[3];
  const float* bihp = (const float*)d_in[4];
  const float* bhhp = (const float*)d_in[5];
  const float* Wout = (const float*)d_in[6];
  const float* bout = (const float*)d_in[7];
  float* out = (float*)d_out;
  char* ws = (char*)d_ws;
  (void)in_sizes; (void)n_in; (void)out_size;
  if (ws_size < WS_NEED) return;

  hipFuncSetAttribute((const void*)lstm_fused,
                      hipFuncAttributeMaxDynamicSharedMemorySize, 163840);

  zero_kernel<<<642, 256, 0, stream>>>(ws);
  xprep_kernel<<<512, 256, 0, stream>>>(X, ws);
  wsprep_kernel<<<3456, 256, 0, stream>>>(Wih, ws);
  lstm_fused<<<256, 256, 163840, stream>>>(X, Wih0, Wih, Whh, bihp, bhhp,
                                           Wout, bout, out, ws);
}

// Round 9
// 2895.461 us; speedup vs baseline: 2.2913x; 1.2702x over previous
//
#include <hip/hip_runtime.h>
#include <hip/hip_fp16.h>
#include <stdint.h>

typedef _Float16 h8 __attribute__((ext_vector_type(8)));
typedef float f4 __attribute__((ext_vector_type(4)));

#define MFMA16(a,b,c) __builtin_amdgcn_mfma_f32_16x16x32_f16((a),(b),(c),0,0,0)

// ---------------- ws memory map ----------------
constexpr size_t XT_OFF = 0;                       // [256 t][8 kg][64 b][8h] fp16
constexpr size_t XT_BYTES = 256ull * 4096 * 2;
constexpr size_t HL_OFF = XT_OFF + XT_BYTES;       // plain h rings [10 L][8 slot][64KB]
constexpr size_t HL_BYTES = 10ull * 8 * 65536;
constexpr size_t HX_OFF = HL_OFF + HL_BYTES;       // sc1 h rings (odd L) [5][8][64KB]
constexpr size_t HX_BYTES = 5ull * 8 * 65536;
constexpr size_t WSTRM_OFF = HX_OFF + HX_BYTES;    // streamed W frags [144 cu][13 s][8 nt][1KB]
constexpr size_t WSTRM_BYTES = 144ull * 106496;
constexpr size_t PX_OFF = WSTRM_OFF + WSTRM_BYTES; // progX[168] sc1 flags
constexpr size_t CNT_OFF = PX_OFF + 1024;
constexpr size_t DIAG_OFF = CNT_OFF + 64;
constexpr size_t WS_NEED = DIAG_OFF + 64;

#define SCR 155648   // LDS scratch for epilogue transpose (4KB)

// ---------------- asm load/store helpers ----------------
__device__ __forceinline__ h8 gld16_p(const void* base, int voff) {
  h8 v; asm volatile("global_load_dwordx4 %0, %1, %2" : "=v"(v) : "v"(voff), "s"(base)); return v;
}
__device__ __forceinline__ h8 gld16_sc1(const void* base, int voff) {
  h8 v; asm volatile("global_load_dwordx4 %0, %1, %2 sc1" : "=v"(v) : "v"(voff), "s"(base)); return v;
}
__device__ __forceinline__ void gst16_sc1(const void* base, int voff, h8 v) {
  asm volatile("global_store_dwordx4 %0, %1, %2 sc1" :: "v"(voff), "v"(v), "s"(base) : "memory");
}
#define WAITI(n) do { asm volatile("s_waitcnt vmcnt(" #n ")" ::: "memory"); \
                      __builtin_amdgcn_sched_barrier(0); } while (0)

__device__ __forceinline__ int ld_prog(const int* p) {
  return __hip_atomic_load(p, __ATOMIC_RELAXED, __HIP_MEMORY_SCOPE_AGENT);
}
__device__ __forceinline__ void st_prog(int* p, int v) {
  __hip_atomic_store(p, v, __ATOMIC_RELAXED, __HIP_MEMORY_SCOPE_AGENT);
  __builtin_amdgcn_sched_barrier(0);
}
#define INV_L1() asm volatile("buffer_inv sc0\n\ts_waitcnt vmcnt(0)" ::: "memory")

__device__ __forceinline__ float sigm(float x) { return __fdividef(1.f, 1.f + __expf(-x)); }
__device__ __forceinline__ float tanh_f(float x) { return 1.f - __fdividef(2.f, __expf(2.f*x) + 1.f); }

// ---------------- prep kernels ----------------
__global__ __launch_bounds__(256) void zero_kernel(char* ws) {
  int i = blockIdx.x * 256 + threadIdx.x;
  if (i < 163840) {
    int layer = i >> 14, w = i & 16383;
    ((int*)(ws + HL_OFF))[(size_t)layer * 8 * 16384 + w] = 0;
  } else {
    int j = i - 163840;
    if (j < 168) ((int*)(ws + PX_OFF))[j] = -1;
    else if (j < 176) ((int*)(ws + CNT_OFF))[j - 168] = 0;
    else if (j == 176) ((int*)(ws + DIAG_OFF))[0] = 0;
  }
}

__global__ __launch_bounds__(256) void xprep_kernel(const float* __restrict__ X, char* ws) {
  int u = blockIdx.x * 256 + threadIdx.x;
  if (u >= 131072) return;
  int t = u >> 9, rem = u & 511, kg = rem >> 6, b = rem & 63;
  const float* src = X + ((size_t)b * 256 + t) * 64 + kg * 8;
  h8 v;
#pragma unroll
  for (int j = 0; j < 8; ++j) v[j] = (_Float16)src[j];
  *(h8*)(ws + XT_OFF + (size_t)u * 16) = v;
}

// pack streamed kt 4..16 (s=0..12) into per-lane fragment layout
__global__ __launch_bounds__(256) void wsprep_kernel(const float* __restrict__ Wih,
                                                     const float* __restrict__ Whh, char* ws) {
  int u = blockIdx.x * 256 + threadIdx.x;
  if (u >= 144 * 6656) return;
  int cu = u / 6656, rem = u % 6656;
  int s = rem / 512, rem2 = rem % 512;
  int nt = rem2 >> 6, l = rem2 & 63;
  int ppc = l >> 2, lgc = l & 3;
  int L = 1 + cu / 16, cl = cu % 16, hbase = cl * 32;
  int kt = 4 + s, k = kt * 32 + lgc * 8;
  int row = (nt & 3) * 512 + hbase + ((nt >> 2) << 4) + ppc;
  const float* src = (k < 512) ? (Wih + (size_t)(L - 1) * 1048576 + (size_t)row * 512 + k)
                               : (Whh + (size_t)L * 1048576 + (size_t)row * 512 + (k - 512));
  h8 v;
#pragma unroll
  for (int j = 0; j < 8; ++j) v[j] = (_Float16)src[j];
  uint32_t off = (uint32_t)(ppc * 64 + lgc * 16) ^ (uint32_t)((ppc & 7) << 4);
  *(h8*)(ws + WSTRM_OFF + (size_t)cu * 106496 + (size_t)s * 8192 + (size_t)nt * 1024 + off) = v;
}

// ---------------- main persistent kernel ----------------
#define KTRES(r, Areg) do {                                                     \
  _Pragma("unroll") for (int nt_ = 0; nt_ < 8; ++nt_) {                         \
    h8 bv_ = *(const h8*)(lds + ((((r) * 8 + nt_) << 10) + swzo));              \
    acc[nt_] = MFMA16((Areg), bv_, acc[nt_]); } } while (0)

#define KTSTR(s, Areg) do {                                                     \
  _Pragma("unroll") for (int nt_ = 0; nt_ < 8; ++nt_)                           \
    acc[nt_] = MFMA16((Areg), Bst[s][nt_], acc[nt_]); } while (0)

#define ISSB(s) do { _Pragma("unroll") for (int nt_ = 0; nt_ < 8; ++nt_)        \
    Bst[s][nt_] = gld16_p(strm, (s) * 8192 + (nt_ << 10) + (int)swzo); } while (0)

#define ISSAS(i0) do { _Pragma("unroll") for (int i_ = 0; i_ < 4; ++i_)         \
    AS[(i0) + i_] = gld16_p(selb, ((i0) + i_) * 4096 + abb); } while (0)

__global__ __launch_bounds__(256, 1) void lstm_fused(
    const float* __restrict__ X, const float* __restrict__ Wih0,
    const float* __restrict__ Wih, const float* __restrict__ Whh,
    const float* __restrict__ bih, const float* __restrict__ bhh,
    const float* __restrict__ Wout, const float* __restrict__ bout,
    float* __restrict__ out, char* __restrict__ ws)
{
  extern __shared__ char lds[];
  const int tid = threadIdx.x;
  const int lane = tid & 63;
  const int wv = tid >> 6;
  const int pp = lane & 15;
  const int lg = lane >> 4;
  const int abb = lg * 1024 + (16 * wv + pp) * 16;
  const uint32_t swzo = (uint32_t)(pp * 64 + lg * 16) ^ (uint32_t)((pp & 7) << 4);

  int* progX = (int*)(ws + PX_OFF);
  int* diag  = (int*)(ws + DIAG_OFF);

  int xcd;
  asm volatile("s_getreg_b32 %0, hwreg(HW_REG_XCC_ID)" : "=s"(xcd));
  xcd &= 7;
  if (tid == 0) {
    int s = atomicAdd((int*)(ws + CNT_OFF) + xcd, 1);
    *(int*)lds = s;
  }
  __syncthreads();
  const int slot = *(int*)lds;
  __syncthreads();

  // ================= head (XCD 5, slots 0..7) =================
  if (xcd == 5) {
    if (slot >= 8) return;
    const int hd = slot, d0 = hd * 8;
    const float* wrow0 = Wout + (size_t)(d0 + wv) * 512;
    const float* wrow1 = Wout + (size_t)(d0 + 4 + wv) * 512;
    const int b = lane;
    const bool pv = lane < 16;
    const int* pw = progX + 144 + (lane & 15);
    for (int th = 0; th < 256; ++th) {
      if (wv == 0) {
        int it = 0; bool bailed = false;
        for (;;) {
          int v = ld_prog(pw);
          if (__ballot(!pv || v >= th) == ~0ull) break;
          __builtin_amdgcn_s_sleep(1);
          if (++it > 60000) { bailed = true; break; }
        }
        if (bailed && lane == 0) atomicMax(diag, 10000 + th);
      }
      __builtin_amdgcn_s_barrier();
      const char* h9 = ws + HX_OFF + (size_t)(4 * 8 + ((th + 1) & 7)) * 65536;
      h8 H0[16], H1[16], H2[16], H3[16];
#pragma unroll
      for (int i = 0; i < 16; ++i) H0[i] = gld16_sc1(h9, i * 1024 + b * 16);
#pragma unroll
      for (int i = 0; i < 16; ++i) H1[i] = gld16_sc1(h9, (16 + i) * 1024 + b * 16);
      float a0 = bout[d0 + wv], a1 = bout[d0 + 4 + wv];
#define KH(kb, H) do { _Pragma("unroll") for (int i_ = 0; i_ < 16; ++i_) {      \
        h8 hv_ = H[i_]; float hf_[8];                                           \
        _Pragma("unroll") for (int j_ = 0; j_ < 8; ++j_) hf_[j_] = (float)hv_[j_]; \
        int kg_ = (kb) + i_;                                                    \
        f4 w0_ = *(const f4*)(wrow0 + kg_ * 8); f4 w1_ = *(const f4*)(wrow0 + kg_ * 8 + 4); \
        a0 += hf_[0]*w0_[0]+hf_[1]*w0_[1]+hf_[2]*w0_[2]+hf_[3]*w0_[3]           \
            + hf_[4]*w1_[0]+hf_[5]*w1_[1]+hf_[6]*w1_[2]+hf_[7]*w1_[3];          \
        f4 u0_ = *(const f4*)(wrow1 + kg_ * 8); f4 u1_ = *(const f4*)(wrow1 + kg_ * 8 + 4); \
        a1 += hf_[0]*u0_[0]+hf_[1]*u0_[1]+hf_[2]*u0_[2]+hf_[3]*u0_[3]           \
            + hf_[4]*u1_[0]+hf_[5]*u1_[1]+hf_[6]*u1_[2]+hf_[7]*u1_[3]; } } while (0)
      WAITI(16); KH(0, H0);
#pragma unroll
      for (int i = 0; i < 16; ++i) H2[i] = gld16_sc1(h9, (32 + i) * 1024 + b * 16);
      WAITI(16); KH(16, H1);
#pragma unroll
      for (int i = 0; i < 16; ++i) H3[i] = gld16_sc1(h9, (48 + i) * 1024 + b * 16);
      WAITI(16); KH(32, H2);
      WAITI(0);  KH(48, H3);
      out[(size_t)b * 16384 + (size_t)th * 64 + d0 + wv] = a0;
      out[(size_t)b * 16384 + (size_t)th * 64 + d0 + 4 + wv] = a1;
      __syncthreads();
      if (tid == 0) st_prog(progX + 160 + hd, th);
    }
    if (hd == 0 && tid == 0) {
      int dv = ld_prog(diag);
      if (dv != 0) out[0] = 1.0e6f + (float)dv;
    }
    return;
  }
  if (xcd > 5 || slot >= 32) return;

  // ================= layer CUs: XCD k hosts layers 2k, 2k+1 =================
  const int L = 2 * xcd + (slot >= 16);
  const int cl = slot & 15;
  const int hbase = cl * 32;
  const bool oddL = (L & 1) != 0;

  // ---- stage resident weights into LDS ----
  if (L == 0) {
    for (int ch = tid; ch < 9216; ch += 256) {   // 18 r: 0,1=x(Wih0) 2..17=h(Whh0)
      int r = ch >> 9, rem = ch & 511;
      int nt = rem >> 6, l = rem & 63, ppc = l >> 2, lgc = l & 3;
      int k = r * 32 + lgc * 8;
      int row = (nt & 3) * 512 + hbase + ((nt >> 2) << 4) + ppc;
      const float* src = (k < 64) ? (Wih0 + (size_t)row * 64 + k)
                                  : (Whh + (size_t)row * 512 + (k - 64));
      h8 v;
#pragma unroll
      for (int j = 0; j < 8; ++j) v[j] = (_Float16)src[j];
      uint32_t off = (uint32_t)(ppc * 64 + lgc * 16) ^ (uint32_t)((ppc & 7) << 4);
      *(h8*)(lds + ((r * 8 + nt) << 10) + off) = v;
    }
  } else {
    const float* WihL = Wih + (size_t)(L - 1) * 1048576;
    const float* WhhL = Whh + (size_t)L * 1048576;
    for (int ch = tid; ch < 9728; ch += 256) {   // 19 r: 0..3 -> kt0..3, 4..18 -> kt17..31
      int r = ch >> 9, rem = ch & 511;
      int nt = rem >> 6, l = rem & 63, ppc = l >> 2, lgc = l & 3;
      int rkt = r < 4 ? r : r + 13;
      int k = rkt * 32 + lgc * 8;
      int row = (nt & 3) * 512 + hbase + ((nt >> 2) << 4) + ppc;
      const float* src = (k < 512) ? (WihL + (size_t)row * 512 + k)
                                   : (WhhL + (size_t)row * 512 + (k - 512));
      h8 v;
#pragma unroll
      for (int j = 0; j < 8; ++j) v[j] = (_Float16)src[j];
      uint32_t off = (uint32_t)(ppc * 64 + lgc * 16) ^ (uint32_t)((ppc & 7) << 4);
      *(h8*)(lds + ((r * 8 + nt) << 10) + off) = v;
    }
  }
  float biasv[8];
#pragma unroll
  for (int nt = 0; nt < 8; ++nt) {
    int row = (nt & 3) * 512 + hbase + ((nt >> 2) << 4) + pp;
    biasv[nt] = bih[L * 2048 + row] + bhh[L * 2048 + row];
  }
  __syncthreads();

  // ---- poll descriptors ----
  const int jl = lane & 15;
  const int* pw = progX; bool pv = false; int dlt = 0;
  if (lane < 16)      { pv = true; pw = progX + L * 16 + jl; dlt = -1; }
  else if (lane < 32) { if (L > 0) { pv = true; pw = progX + (L - 1) * 16 + jl; dlt = 0; } }
  else if (lane < 48) {
    dlt = -7;
    if (L == 9) { if (jl < 8) { pv = true; pw = progX + 160 + jl; } }
    else        { pv = true; pw = progX + (L + 1) * 16 + jl; }
  }

  const char* hl = ws + HL_OFF;
  const char* hx = ws + HX_OFF;
  const char* strm = ws + WSTRM_OFF + (size_t)((L - 1) * 16 + cl) * 106496;
  const char* xt = ws + XT_OFF;

  float cv[2][4] = {{0,0,0,0},{0,0,0,0}};

  for (int t = 0; t < 256; ++t) {
    if (wv == 0) {
      int it = 0; bool bailed = false;
      for (;;) {
        int v = ld_prog(pw);
        if (__ballot(!pv || v >= t + dlt) == ~0ull) break;
        __builtin_amdgcn_s_sleep(1);
        if (++it > 60000) { bailed = true; break; }
      }
      if (bailed && lane == 0) atomicMax(diag, L * 1000 + t);
      INV_L1();
    }
    __builtin_amdgcn_s_barrier();

    f4 acc[8];
#pragma unroll
    for (int j = 0; j < 8; ++j) acc[j] = (f4){0.f, 0.f, 0.f, 0.f};

    if (L == 0) {
      const char* selb = hl + (size_t)(t & 7) * 65536;
      h8 X0 = gld16_p(xt, t * 8192 + abb);
      h8 X1 = gld16_p(xt, t * 8192 + 4096 + abb);
      h8 AS[16];
#pragma unroll
      for (int i = 0; i < 16; ++i) AS[i] = gld16_p(selb, i * 4096 + abb);
      WAITI(17); KTRES(0, X0);
      WAITI(16); KTRES(1, X1);
      WAITI(15); KTRES(2, AS[0]);  WAITI(14); KTRES(3, AS[1]);
      WAITI(13); KTRES(4, AS[2]);  WAITI(12); KTRES(5, AS[3]);
      WAITI(11); KTRES(6, AS[4]);  WAITI(10); KTRES(7, AS[5]);
      WAITI(9);  KTRES(8, AS[6]);  WAITI(8);  KTRES(9, AS[7]);
      WAITI(7);  KTRES(10, AS[8]); WAITI(6);  KTRES(11, AS[9]);
      WAITI(5);  KTRES(12, AS[10]); WAITI(4); KTRES(13, AS[11]);
      WAITI(3);  KTRES(14, AS[12]); WAITI(2); KTRES(15, AS[13]);
      WAITI(1);  KTRES(16, AS[14]); WAITI(0); KTRES(17, AS[15]);
    } else {
      const char* botb = oddL ? (hl + (size_t)((L - 1) * 8 + ((t + 1) & 7)) * 65536)
                              : (hx + (size_t)(((L - 1) >> 1) * 8 + ((t + 1) & 7)) * 65536);
      const char* selb = hl + (size_t)(L * 8 + (t & 7)) * 65536;
      h8 AB[16], AS[16], Bst[13][8];
      if (oddL) {
#pragma unroll
        for (int i = 0; i < 16; ++i) AB[i] = gld16_p(botb, i * 4096 + abb);
      } else {
#pragma unroll
        for (int i = 0; i < 16; ++i) AB[i] = gld16_sc1(botb, i * 4096 + abb);
      }
      ISSB(0); ISSB(1);                                  // out 32
      WAITI(31); KTRES(0, AB[0]); ISSB(2);               // AB0       (out 39)
      WAITI(38); KTRES(1, AB[1]); ISSB(3);               // AB1       (out 46)
      WAITI(45); KTRES(2, AB[2]); ISSB(4);               // AB2       (out 53)
      WAITI(52); KTRES(3, AB[3]); ISSB(5);               // AB3       (out 60)
      WAITI(40); KTSTR(0, AB[4]); ISSB(6);               // AB4..15 + Bst0 (48)
      WAITI(40); KTSTR(1, AB[5]); ISSB(7);               // Bst1
      WAITI(40); KTSTR(2, AB[6]); ISSB(8);               // Bst2
      WAITI(40); KTSTR(3, AB[7]); ISSB(9);               // Bst3
      WAITI(40); KTSTR(4, AB[8]); ISSB(10);              // Bst4
      WAITI(40); KTSTR(5, AB[9]); ISSB(11);              // Bst5
      WAITI(40); KTSTR(6, AB[10]); ISSB(12);             // Bst6      (out 48)
      WAITI(40); KTSTR(7, AB[11]); ISSAS(0);             // Bst7      (out 44)
      WAITI(36); KTSTR(8, AB[12]); ISSAS(4);             // Bst8      (out 40)
      WAITI(28); KTSTR(9, AB[13]); ISSAS(8);             // Bst9+AS0..3 (32)
      WAITI(20); KTSTR(10, AB[14]); ISSAS(12);           // Bst10+AS4..7 (24)
      WAITI(12); KTSTR(11, AB[15]);                      // Bst11+AS8..11
      WAITI(4);  KTSTR(12, AS[0]);                       // Bst12
      KTRES(4, AS[1]);  KTRES(5, AS[2]);  KTRES(6, AS[3]);
      KTRES(7, AS[4]);  KTRES(8, AS[5]);  KTRES(9, AS[6]);
      KTRES(10, AS[7]); KTRES(11, AS[8]); KTRES(12, AS[9]);
      KTRES(13, AS[10]); KTRES(14, AS[11]);
      WAITI(3); KTRES(15, AS[12]);
      WAITI(2); KTRES(16, AS[13]);
      WAITI(1); KTRES(17, AS[14]);
      WAITI(0); KTRES(18, AS[15]);
    }

    // ---- epilogue: gates -> LDS transpose -> wide coalesced stores ----
    const int brow = 16 * wv + 4 * lg;
#pragma unroll
    for (int jh = 0; jh < 2; ++jh) {
      const int hgl = jh * 16 + pp;
#pragma unroll
      for (int r = 0; r < 4; ++r) {
        float gi = sigm(acc[4*jh+0][r] + biasv[4*jh+0]);
        float gf = sigm(acc[4*jh+1][r] + biasv[4*jh+1]);
        float gg = tanh_f(acc[4*jh+2][r] + biasv[4*jh+2]);
        float go = sigm(acc[4*jh+3][r] + biasv[4*jh+3]);
        float cc = gf * cv[jh][r] + gi * gg;
        cv[jh][r] = cc;
        float hh = go * tanh_f(cc);
        *(_Float16*)(lds + SCR + ((hgl >> 3) << 10) + (brow + r) * 16 + ((hgl & 7) << 1))
            = (_Float16)hh;
      }
    }
    __syncthreads();
    {
      const int kg_l = tid >> 6, b = tid & 63;
      h8 vv = *(const h8*)(lds + SCR + tid * 16);
      const int goff = (((hbase >> 3) + kg_l) << 10) + b * 16;
      char* HdL = (char*)(hl + (size_t)(L * 8 + ((t + 1) & 7)) * 65536);
      *(h8*)(HdL + goff) = vv;                              // plain -> home L2
      if (oddL) {
        const char* HdX = hx + (size_t)((L >> 1) * 8 + ((t + 1) & 7)) * 65536;
        gst16_sc1(HdX, goff, vv);                           // coherent -> L3
      }
    }
    asm volatile("s_waitcnt vmcnt(0)" ::: "memory");        // h stores acked
    __syncthreads();
    if (tid == 0) st_prog(progX + L * 16 + cl, t);
  }
}

// ---------------- host ----------------
extern "C" void kernel_launch(void* const* d_in, const int* in_sizes, int n_in,
                              void* d_out, int out_size, void* d_ws, size_t ws_size,
                              hipStream_t stream) {
  const float* X    = (const float*)d_in[0];
  const float* Wih0 = (const float*)d_in[1];
  const float* Wih  = (const float*)d_in[2];
  const float* Whh  = (const float*)d_in[3];
  const float* bihp = (const float*)d_in[4];
  const float* bhhp = (const float*)d_in[5];
  const float* Wout = (const float*)d_in[6];
  const float* bout = (const float*)d_in[7];
  float* out = (float*)d_out;
  char* ws = (char*)d_ws;
  (void)in_sizes; (void)n_in; (void)out_size;
  if (ws_size < WS_NEED) return;

  hipFuncSetAttribute((const void*)lstm_fused,
                      hipFuncAttributeMaxDynamicSharedMemorySize, 163840);

  zero_kernel<<<642, 256, 0, stream>>>(ws);
  xprep_kernel<<<512, 256, 0, stream>>>(X, ws);
  wsprep_kernel<<<3744, 256, 0, stream>>>(Wih, Whh, ws);
  lstm_fused<<<256, 256, 163840, stream>>>(X, Wih0, Wih, Whh, bihp, bhhp,
                                           Wout, bout, out, ws);
}